// Round 7
// baseline (160.342 us; speedup 1.0000x reference)
//
#include <hip/hip_runtime.h>
#include <math.h>

// Problem dims (fixed by the reference)
constexpr int NB  = 16;    // batch
constexpr int NP  = 1024;  // prev points
constexpr int NS  = 4096;  // skip points
constexpr int CP  = 256;   // prev channels
constexpr int CS  = 128;   // skip channels
constexpr int CIN = 384;   // CP + CS
constexpr int CO  = 256;   // output channels

constexpr int NCHUNK = 16;          // prev-point chunks for topk parallelism
constexpr int CHPTS  = NP / NCHUNK; // 64

typedef unsigned int uint;
typedef unsigned short ushort_t;
typedef __attribute__((ext_vector_type(8))) short short8;
typedef __attribute__((ext_vector_type(8))) unsigned short us8;
typedef __attribute__((ext_vector_type(4))) float f32x4;

__device__ __forceinline__ ushort_t f2bf(float f) {
  uint u = __float_as_uint(f);
  uint r = (u + 0x7fffu + ((u >> 16) & 1u)) >> 16;   // RNE
  return (ushort_t)r;
}
__device__ __forceinline__ float bf2f(ushort_t u) {
  return __uint_as_float(((uint)u) << 16);
}

__device__ __forceinline__ void gload16(const void* g, void* l) {
  __builtin_amdgcn_global_load_lds(
      (const __attribute__((address_space(1))) uint*)g,
      (__attribute__((address_space(3))) uint*)l, 16, 0, 0);
}

// Packed-key top-3 step (see round-5 notes: set-level correctness is what
// matters; masked-dist error <= 2^-13 relative).
__device__ __forceinline__ void tkp(float pxv, float pyv, float pzv, int pi,
                                    float qx, float qy, float qz,
                                    float& k0, float& k1, float& k2,
                                    float& rsum) {
  float dx = pxv - qx, dy = pyv - qy, dz = pzv - qz;
  float sq = fmaf(dz, dz, fmaf(dy, dy, fmaf(dx, dx, 1e-16f)));
  rsum += __builtin_amdgcn_rsqf(sq);
  float k = __uint_as_float((__float_as_uint(sq) & 0xFFFFFC00u) | (uint)pi);
  k2 = __builtin_amdgcn_fmed3f(k1, k2, k);
  k1 = __builtin_amdgcn_fmed3f(k0, k1, k);
  k0 = fminf(k0, k);
}

// ---------------------------------------------------------------------------
// topk stage 1 (unchanged from round 5)
__global__ __launch_bounds__(256) void topk_chunk_kernel(
    const float* __restrict__ xyz_prev, const float* __restrict__ xyz_skip,
    float* __restrict__ pbuf) {
  __shared__ float px[CHPTS], py[CHPTS], pz[CHPTS];
  int q  = blockIdx.y;
  int b  = blockIdx.z;
  int tid = threadIdx.x;
  if (tid < CHPTS) {
    const float* xp = xyz_prev + ((size_t)b * NP + q * CHPTS + tid) * 3;
    px[tid] = xp[0]; py[tid] = xp[1]; pz[tid] = xp[2];
  }
  __syncthreads();
  int nA = blockIdx.x * 512 + tid;
  int nB = nA + 256;
  const float* xqA = xyz_skip + ((size_t)b * NS + nA) * 3;
  const float* xqB = xyz_skip + ((size_t)b * NS + nB) * 3;
  float qxA = xqA[0], qyA = xqA[1], qzA = xqA[2];
  float qxB = xqB[0], qyB = xqB[1], qzB = xqB[2];
  float kA0 = INFINITY, kA1 = INFINITY, kA2 = INFINITY;
  float kB0 = INFINITY, kB1 = INFINITY, kB2 = INFINITY;
  float rsA = 0.f, rsB = 0.f;
  int pbase = q * CHPTS;
  for (int p = 0; p < CHPTS; p += 4) {
    float4 X = *(const float4*)&px[p];
    float4 Y = *(const float4*)&py[p];
    float4 Z = *(const float4*)&pz[p];
    tkp(X.x, Y.x, Z.x, pbase + p + 0, qxA, qyA, qzA, kA0, kA1, kA2, rsA);
    tkp(X.x, Y.x, Z.x, pbase + p + 0, qxB, qyB, qzB, kB0, kB1, kB2, rsB);
    tkp(X.y, Y.y, Z.y, pbase + p + 1, qxA, qyA, qzA, kA0, kA1, kA2, rsA);
    tkp(X.y, Y.y, Z.y, pbase + p + 1, qxB, qyB, qzB, kB0, kB1, kB2, rsB);
    tkp(X.z, Y.z, Z.z, pbase + p + 2, qxA, qyA, qzA, kA0, kA1, kA2, rsA);
    tkp(X.z, Y.z, Z.z, pbase + p + 2, qxB, qyB, qzB, kB0, kB1, kB2, rsB);
    tkp(X.w, Y.w, Z.w, pbase + p + 3, qxA, qyA, qzA, kA0, kA1, kA2, rsA);
    tkp(X.w, Y.w, Z.w, pbase + p + 3, qxB, qyB, qzB, kB0, kB1, kB2, rsB);
  }
  size_t PA = ((size_t)(b * NCHUNK + q) * NS + nA) * 4;
  size_t PB = ((size_t)(b * NCHUNK + q) * NS + nB) * 4;
  *(float4*)(pbuf + PA) = make_float4(kA0, kA1, kA2, rsA);
  *(float4*)(pbuf + PB) = make_float4(kB0, kB1, kB2, rsB);
}

// topk stage 2 (unchanged)
__global__ __launch_bounds__(256) void topk_merge_kernel(
    const float* __restrict__ pbuf, float* __restrict__ w3,
    int* __restrict__ idx3) {
  int gid = blockIdx.x * 256 + threadIdx.x;  // = b*NS + n
  int b = gid >> 12;
  int n = gid & (NS - 1);
  float k0 = INFINITY, k1 = INFINITY, k2 = INFINITY;
  float rsum = 0.f;
  #pragma unroll 4
  for (int q = 0; q < NCHUNK; q++) {
    float4 v = *(const float4*)(pbuf + ((size_t)(b * NCHUNK + q) * NS + n) * 4);
    rsum += v.w;
    k2 = __builtin_amdgcn_fmed3f(k1, k2, v.x);
    k1 = __builtin_amdgcn_fmed3f(k0, k1, v.x);
    k0 = fminf(k0, v.x);
    k2 = __builtin_amdgcn_fmed3f(k1, k2, v.y);
    k1 = __builtin_amdgcn_fmed3f(k0, k1, v.y);
    k0 = fminf(k0, v.y);
    k2 = __builtin_amdgcn_fmed3f(k1, k2, v.z);
    k1 = __builtin_amdgcn_fmed3f(k0, k1, v.z);
    k0 = fminf(k0, v.z);
  }
  float inv = 1.0f / rsum;
  uint u0 = __float_as_uint(k0), u1 = __float_as_uint(k1), u2 = __float_as_uint(k2);
  float d0 = __uint_as_float(u0 & 0xFFFFFC00u);
  float d1 = __uint_as_float(u1 & 0xFFFFFC00u);
  float d2 = __uint_as_float(u2 & 0xFFFFFC00u);
  size_t base = (size_t)gid * 3;
  w3[base + 0] = __builtin_amdgcn_rsqf(d0) * inv;
  w3[base + 1] = __builtin_amdgcn_rsqf(d1) * inv;
  w3[base + 2] = __builtin_amdgcn_rsqf(d2) * inv;
  idx3[base + 0] = (int)(u0 & 1023u);
  idx3[base + 1] = (int)(u1 & 1023u);
  idx3[base + 2] = (int)(u2 & 1023u);
}

// ---------------------------------------------------------------------------
// W fp32 -> bf16; block 0 also zeros the BN stats.
__global__ __launch_bounds__(256) void wcast_kernel(
    const float* __restrict__ W1, const float* __restrict__ W2,
    ushort_t* __restrict__ W1b, ushort_t* __restrict__ W2b,
    float* __restrict__ st1, float* __restrict__ st2) {
  int tid = threadIdx.x;
  if (blockIdx.x == 0) {
    st1[tid] = 0.f; st1[tid + 256] = 0.f;
    st2[tid] = 0.f; st2[tid + 256] = 0.f;
  }
  int t = blockIdx.x * 256 + tid;
  int n1 = CO * CIN / 4;
  if (t < n1) {
    float4 v = *(const float4*)(W1 + t * 4);
    ushort4 o; o.x = f2bf(v.x); o.y = f2bf(v.y); o.z = f2bf(v.z); o.w = f2bf(v.w);
    *(ushort4*)(W1b + t * 4) = o;
  } else {
    int u = t - n1;
    float4 v = *(const float4*)(W2 + u * 4);
    ushort4 o; o.x = f2bf(v.x); o.y = f2bf(v.y); o.z = f2bf(v.z); o.w = f2bf(v.w);
    *(ushort4*)(W2b + u * 4) = o;
  }
}

// ---------------------------------------------------------------------------
// Transpose points_prev [b][256][1024] f32 -> pptT [b][1024][256] bf16.
__global__ __launch_bounds__(256) void ppT_kernel(
    const float* __restrict__ pp, ushort_t* __restrict__ pptT) {
  __shared__ float tl[64][65];
  int p0 = blockIdx.x * 64, c0 = blockIdx.y * 64, b = blockIdx.z;
  int tid = threadIdx.x;
  const float* P = pp + (size_t)b * CP * NP;
  int pi4 = (tid & 15) * 4, ci = tid >> 4;
  #pragma unroll
  for (int r = 0; r < 4; r++) {
    int cc = ci + 16 * r;
    float4 v = *(const float4*)(P + (size_t)(c0 + cc) * NP + p0 + pi4);
    tl[cc][pi4] = v.x; tl[cc][pi4 + 1] = v.y; tl[cc][pi4 + 2] = v.z; tl[cc][pi4 + 3] = v.w;
  }
  __syncthreads();
  ushort_t* O = pptT + (size_t)b * NP * CP;
  int ci4 = (tid & 15) * 4, pi = tid >> 4;
  #pragma unroll
  for (int r = 0; r < 4; r++) {
    int pr = pi + 16 * r;
    ushort4 o;
    o.x = f2bf(tl[ci4 + 0][pr]); o.y = f2bf(tl[ci4 + 1][pr]);
    o.z = f2bf(tl[ci4 + 2][pr]); o.w = f2bf(tl[ci4 + 3][pr]);
    *(ushort4*)(O + (size_t)(p0 + pr) * CP + c0 + ci4) = o;
  }
}

// Transpose points_skip [b][128][4096] f32 -> xsk [b][n][128] bf16.
__global__ __launch_bounds__(256) void skipT_kernel(
    const float* __restrict__ sk, ushort_t* __restrict__ xsk) {
  __shared__ float tl[64][65];
  int n0 = blockIdx.x * 64, c0 = blockIdx.y * 64, b = blockIdx.z;
  int tid = threadIdx.x;
  const float* S = sk + (size_t)b * CS * NS;
  int ni4 = (tid & 15) * 4, ci = tid >> 4;
  #pragma unroll
  for (int r = 0; r < 4; r++) {
    int cc = ci + 16 * r;
    float4 v = *(const float4*)(S + (size_t)(c0 + cc) * NS + n0 + ni4);
    tl[cc][ni4] = v.x; tl[cc][ni4 + 1] = v.y; tl[cc][ni4 + 2] = v.z; tl[cc][ni4 + 3] = v.w;
  }
  __syncthreads();
  ushort_t* O = xsk + (size_t)b * NS * CS;
  int ci4 = (tid & 15) * 4, ni = tid >> 4;
  #pragma unroll
  for (int r = 0; r < 4; r++) {
    int nr = ni + 16 * r;
    ushort4 o;
    o.x = f2bf(tl[ci4 + 0][nr]); o.y = f2bf(tl[ci4 + 1][nr]);
    o.z = f2bf(tl[ci4 + 2][nr]); o.w = f2bf(tl[ci4 + 3][nr]);
    *(ushort4*)(O + (size_t)(n0 + nr) * CS + c0 + ci4) = o;
  }
}

// ---------------------------------------------------------------------------
// Fused MFMA GEMM with 2-phase pipeline (counted vmcnt, raw barriers).
// MODE 0: gemm1 — X rows built on the fly: c<256 gathered from pptT via
//         (idx3,w3), c>=256 read from xsk. KD=384, NT=12.
// MODE 1: gemm2 — X = relu(a1*y1+s1) from y1b, affine computed from stats
//         in the prologue. KD=256, NT=8.
// 128x128 tile, 4 waves, 4x4 frags of 16x16x32, bf16 out + BN stats.
template <int MODE>
__global__ __launch_bounds__(256) void gemm_fused_kernel(
    const ushort_t* __restrict__ Xsrc,   // MODE0: pptT, MODE1: y1b
    const ushort_t* __restrict__ xsk,    // MODE0 only
    const float* __restrict__ w3, const int* __restrict__ idx3,
    const ushort_t* __restrict__ Wb, ushort_t* __restrict__ Yb,
    float* __restrict__ stats,
    const float* __restrict__ stats_in, const float* __restrict__ g_in,
    const float* __restrict__ bt_in) {
  constexpr int KD = (MODE == 0) ? CIN : CO;
  constexpr int NT = KD / 32;
  __shared__ __align__(16) char lds_raw[33792];   // staging 24KB / epi 33KB
  ushort_t* ldsX = (ushort_t*)lds_raw;                    // [128][32]
  ushort_t* ldsW = (ushort_t*)(lds_raw + 8192);           // 2 x [128][32]
  __shared__ float ssum[128], ssq[128];
  __shared__ float a1s[MODE ? CO : 1], s1s[MODE ? CO : 1];

  int tid = threadIdx.x;
  int w = tid >> 6, l = tid & 63;
  int bid = blockIdx.x;
  int by = (bid >> 3) & 1;
  int s  = (bid & 7) + 8 * (bid >> 4);
  int bx = s & 31;
  int bz = s >> 5;
  int n0 = bx * 128;
  if (tid < 128) { ssum[tid] = 0.f; ssq[tid] = 0.f; }
  if constexpr (MODE == 1) {
    float cnt = (float)NB * (float)NS;
    float m = stats_in[tid] / cnt;
    float var = stats_in[CO + tid] / cnt - m * m;
    var = fmaxf(var, 0.f);
    float invs = rsqrtf(var + 1e-5f);
    float av = g_in[tid] * invs;
    a1s[tid] = av; s1s[tid] = bt_in[tid] - m * av;
  }
  __syncthreads();

  // per-thread staging geometry: 2 threads/row, 2 phys 8-elem chunks each
  int r = tid >> 1, h = tid & 1;
  int sw = (r >> 1) & 3;
  int p0c = 2 * h, p1c = 2 * h + 1;
  int cl0 = (p0c ^ sw) * 8, cl1 = (p1c ^ sw) * 8;  // logical c offsets
  // gather row metadata (MODE0)
  int j0 = 0, j1 = 0, j2 = 0; float w0 = 0.f, w1 = 0.f, w2 = 0.f;
  const ushort_t* Pb = nullptr; const ushort_t* Kb = nullptr;
  const ushort_t* Xb = nullptr;
  if constexpr (MODE == 0) {
    size_t nb3 = ((size_t)bz * NS + n0 + r) * 3;
    j0 = idx3[nb3 + 0]; j1 = idx3[nb3 + 1]; j2 = idx3[nb3 + 2];
    w0 = w3[nb3 + 0]; w1 = w3[nb3 + 1]; w2 = w3[nb3 + 2];
    Pb = Xsrc + (size_t)bz * NP * CP;
    Kb = xsk + ((size_t)bz * NS + n0 + r) * CS;
  } else {
    Xb = Xsrc + ((size_t)bz * NS + n0 + r) * KD;
  }
  // W staging (per wave, 2 x 1KB rows-blocks)
  int wrb = w * 16 + (l >> 2);
  int wcl = l & 3;
  int wksw = 8 * (wcl ^ ((wrb >> 1) & 3));

  us8 ra0, rb0, rc0, ra1, rb1, rc1;   // gather regs (MODE0 c<256)
  us8 rg0, rg1;                        // direct regs (skip tiles / MODE1)

  auto issue = [&](int tt) {
    int cb = tt * 32;
    if constexpr (MODE == 0) {
      if (cb < CP) {
        ra0 = *(const us8*)(Pb + (size_t)j0 * CP + cb + cl0);
        rb0 = *(const us8*)(Pb + (size_t)j1 * CP + cb + cl0);
        rc0 = *(const us8*)(Pb + (size_t)j2 * CP + cb + cl0);
        ra1 = *(const us8*)(Pb + (size_t)j0 * CP + cb + cl1);
        rb1 = *(const us8*)(Pb + (size_t)j1 * CP + cb + cl1);
        rc1 = *(const us8*)(Pb + (size_t)j2 * CP + cb + cl1);
      } else {
        rg0 = *(const us8*)(Kb + cb - CP + cl0);
        rg1 = *(const us8*)(Kb + cb - CP + cl1);
      }
    } else {
      rg0 = *(const us8*)(Xb + cb + cl0);
      rg1 = *(const us8*)(Xb + cb + cl1);
    }
    // W tile -> ldsW[tt&1]
    ushort_t* wdst = ldsW + (tt & 1) * (128 * 32);
    int ks = cb + wksw;
    gload16(Wb + (size_t)(by * 128 + wrb) * KD + ks, &wdst[(w * 16) * 32]);
    gload16(Wb + (size_t)(by * 128 + 64 + wrb) * KD + ks, &wdst[(64 + w * 16) * 32]);
  };

  f32x4 acc[4][4];
  #pragma unroll
  for (int i = 0; i < 4; i++)
    #pragma unroll
    for (int j = 0; j < 4; j++) acc[i][j] = {0.f, 0.f, 0.f, 0.f};

  int wn = (w & 1) * 64, wo = (w >> 1) * 64;
  int lr = l & 15, lk = l >> 4;

  issue(0);

  #pragma unroll
  for (int t = 0; t < NT; t++) {
    // --- stage X(t) into LDS from regs (compiler waits the reg loads)
    {
      us8 v0, v1;
      if constexpr (MODE == 0) {
        if (t * 32 < CP) {
          #pragma unroll
          for (int e = 0; e < 8; e++) {
            v0[e] = f2bf(w0 * bf2f(ra0[e]) + w1 * bf2f(rb0[e]) + w2 * bf2f(rc0[e]));
            v1[e] = f2bf(w0 * bf2f(ra1[e]) + w1 * bf2f(rb1[e]) + w2 * bf2f(rc1[e]));
          }
        } else { v0 = rg0; v1 = rg1; }
      } else {
        int c0l = t * 32 + cl0, c1l = t * 32 + cl1;
        float4 a0 = *(const float4*)&a1s[c0l], a0b = *(const float4*)&a1s[c0l + 4];
        float4 s0 = *(const float4*)&s1s[c0l], s0b = *(const float4*)&s1s[c0l + 4];
        float4 a1v = *(const float4*)&a1s[c1l], a1b = *(const float4*)&a1s[c1l + 4];
        float4 s1v = *(const float4*)&s1s[c1l], s1b = *(const float4*)&s1s[c1l + 4];
        const float* a0p = (const float*)&a0; const float* a0bp = (const float*)&a0b;
        const float* s0p = (const float*)&s0; const float* s0bp = (const float*)&s0b;
        const float* a1p = (const float*)&a1v; const float* a1bp = (const float*)&a1b;
        const float* s1p = (const float*)&s1v; const float* s1bp = (const float*)&s1b;
        #pragma unroll
        for (int e = 0; e < 4; e++) {
          v0[e]     = f2bf(fmaxf(fmaf(a0p[e],  bf2f(rg0[e]),     s0p[e]),  0.f));
          v0[e + 4] = f2bf(fmaxf(fmaf(a0bp[e], bf2f(rg0[e + 4]), s0bp[e]), 0.f));
          v1[e]     = f2bf(fmaxf(fmaf(a1p[e],  bf2f(rg1[e]),     s1p[e]),  0.f));
          v1[e + 4] = f2bf(fmaxf(fmaf(a1bp[e], bf2f(rg1[e + 4]), s1bp[e]), 0.f));
        }
      }
      *(us8*)&ldsX[r * 32 + p0c * 8] = v0;
      *(us8*)&ldsX[r * 32 + p1c * 8] = v1;
    }
    // --- issue t+1 loads (X regs + W gload_lds)
    if (t + 1 < NT) issue(t + 1);
    // --- wait: W(t) landed (older than the t+1 issues), own ds_writes done
    if constexpr (MODE == 0) {
      if (t + 1 < 8)        asm volatile("s_waitcnt vmcnt(8) lgkmcnt(0)" ::: "memory");
      else if (t + 1 < NT)  asm volatile("s_waitcnt vmcnt(4) lgkmcnt(0)" ::: "memory");
      else                  asm volatile("s_waitcnt vmcnt(0) lgkmcnt(0)" ::: "memory");
    } else {
      if (t + 1 < NT)       asm volatile("s_waitcnt vmcnt(4) lgkmcnt(0)" ::: "memory");
      else                  asm volatile("s_waitcnt vmcnt(0) lgkmcnt(0)" ::: "memory");
    }
    __builtin_amdgcn_s_barrier();
    __builtin_amdgcn_sched_barrier(0);
    // --- compute from ldsX, ldsW[t&1]
    {
      const ushort_t* Wl = ldsW + (t & 1) * (128 * 32);
      short8 af[4], bf_[4];
      #pragma unroll
      for (int i = 0; i < 4; i++) {
        int rr = wn + i * 16 + lr;
        int cs = lk ^ ((rr >> 1) & 3);
        af[i] = *(const short8*)&ldsX[rr * 32 + cs * 8];
      }
      #pragma unroll
      for (int j = 0; j < 4; j++) {
        int rr = wo + j * 16 + lr;
        int cs = lk ^ ((rr >> 1) & 3);
        bf_[j] = *(const short8*)&Wl[rr * 32 + cs * 8];
      }
      __builtin_amdgcn_s_setprio(1);
      #pragma unroll
      for (int i = 0; i < 4; i++)
        #pragma unroll
        for (int j = 0; j < 4; j++)
          acc[i][j] = __builtin_amdgcn_mfma_f32_16x16x32_bf16(af[i], bf_[j], acc[i][j], 0, 0, 0);
      __builtin_amdgcn_s_setprio(0);
    }
    __builtin_amdgcn_s_barrier();
    __builtin_amdgcn_sched_barrier(0);
  }

  // --- epilogue: stats from regs, tile -> LDS, coalesced row stores
  #pragma unroll
  for (int j = 0; j < 4; j++) {
    int ol = wo + j * 16 + lr;
    float ps = 0.f, pq = 0.f;
    #pragma unroll
    for (int i = 0; i < 4; i++)
      #pragma unroll
      for (int rg = 0; rg < 4; rg++) { float v = acc[i][j][rg]; ps += v; pq += v * v; }
    atomicAdd(&ssum[ol], ps);
    atomicAdd(&ssq[ol], pq);
  }
  ushort_t* lout = (ushort_t*)lds_raw;   // [128][132]
  #pragma unroll
  for (int i = 0; i < 4; i++)
    #pragma unroll
    for (int j = 0; j < 4; j++)
      #pragma unroll
      for (int rg = 0; rg < 4; rg++) {
        int nl = wn + i * 16 + lk * 4 + rg;
        int ol = wo + j * 16 + lr;
        lout[nl * 132 + ol] = f2bf(acc[i][j][rg]);
      }
  __syncthreads();
  {
    int row = tid >> 1, half = tid & 1;
    const ushort_t* src = lout + row * 132 + half * 64;
    ushort_t* dst = Yb + ((size_t)bz * NS + n0 + row) * CO + by * 128 + half * 64;
    #pragma unroll
    for (int k = 0; k < 8; k++)
      *(us8*)(dst + k * 8) = *(const us8*)(src + k * 8);
  }
  if (tid < 128) {
    atomicAdd(&stats[by * 128 + tid], ssum[tid]);
    atomicAdd(&stats[CO + by * 128 + tid], ssq[tid]);
  }
}

// Final BN2+ReLU with transpose, bf16 in [b][n][o] -> f32 out [b][o][n].
__global__ __launch_bounds__(256) void bnrelu_tr_kernel(
    const ushort_t* __restrict__ y2b, const float* __restrict__ stats_in,
    const float* __restrict__ g_in, const float* __restrict__ bt_in,
    float* __restrict__ out) {
  __shared__ float tl[64][65];
  __shared__ float a2s[64], s2s[64];
  int n0 = blockIdx.x * 64, o0 = blockIdx.y * 64, b = blockIdx.z;
  const ushort_t* Y = y2b + (size_t)b * NS * CO;
  int tid = threadIdx.x;
  if (tid < 64) {
    int o = o0 + tid;
    float cnt = (float)NB * (float)NS;
    float m = stats_in[o] / cnt;
    float var = stats_in[CO + o] / cnt - m * m;
    var = fmaxf(var, 0.f);
    float invs = rsqrtf(var + 1e-5f);
    float av = g_in[o] * invs;
    a2s[tid] = av; s2s[tid] = bt_in[o] - m * av;
  }
  int o8 = (tid & 7) * 8, row = tid >> 3;
  #pragma unroll
  for (int r = 0; r < 2; r++) {
    int ii = row + 32 * r;
    const ushort_t* src = Y + (size_t)(n0 + ii) * CO + o0 + o8;
    ushort4 v0 = *(const ushort4*)(src);
    ushort4 v1 = *(const ushort4*)(src + 4);
    tl[ii][o8 + 0] = bf2f(v0.x); tl[ii][o8 + 1] = bf2f(v0.y);
    tl[ii][o8 + 2] = bf2f(v0.z); tl[ii][o8 + 3] = bf2f(v0.w);
    tl[ii][o8 + 4] = bf2f(v1.x); tl[ii][o8 + 5] = bf2f(v1.y);
    tl[ii][o8 + 6] = bf2f(v1.z); tl[ii][o8 + 7] = bf2f(v1.w);
  }
  __syncthreads();
  float* O = out + (size_t)b * CO * NS;
  int ii4 = (tid & 15) * 4, j = tid >> 4;
  #pragma unroll
  for (int r = 0; r < 4; r++) {
    int jj = j + 16 * r;
    float av = a2s[jj], sv = s2s[jj];
    float4 v;
    v.x = fmaxf(fmaf(av, tl[ii4 + 0][jj], sv), 0.f);
    v.y = fmaxf(fmaf(av, tl[ii4 + 1][jj], sv), 0.f);
    v.z = fmaxf(fmaf(av, tl[ii4 + 2][jj], sv), 0.f);
    v.w = fmaxf(fmaf(av, tl[ii4 + 3][jj], sv), 0.f);
    *(float4*)(O + (size_t)(o0 + jj) * NS + n0 + ii4) = v;
  }
}

extern "C" void kernel_launch(void* const* d_in, const int* in_sizes, int n_in,
                              void* d_out, int out_size, void* d_ws, size_t ws_size,
                              hipStream_t stream) {
  const float* xyz_prev    = (const float*)d_in[0];
  const float* xyz_skip    = (const float*)d_in[1];
  const float* points_prev = (const float*)d_in[2];
  const float* points_skip = (const float*)d_in[3];
  const float* W1 = (const float*)d_in[4];
  const float* g1 = (const float*)d_in[5];
  const float* b1 = (const float*)d_in[6];
  const float* W2 = (const float*)d_in[7];
  const float* g2 = (const float*)d_in[8];
  const float* b2 = (const float*)d_in[9];
  float* out = (float*)d_out;

  // workspace layout (256B-aligned sequential allocs)
  char* W = (char*)d_ws;
  size_t off = 0;
  auto alloc = [&](size_t bytes) {
    size_t o = off; off = (off + bytes + 255) & ~(size_t)255; return o;
  };
  ushort_t* xsk  = (ushort_t*)(W + alloc((size_t)NB * NS * CS * 2));   // 12.6MB
  ushort_t* y1b  = (ushort_t*)(W + alloc((size_t)NB * NS * CO * 2));   // 33.6MB
  ushort_t* pptT = (ushort_t*)(W + alloc((size_t)NB * NP * CP * 2));   // 8.4MB
  ushort_t* W1b  = (ushort_t*)(W + alloc((size_t)CO * CIN * 2));
  ushort_t* W2b  = (ushort_t*)(W + alloc((size_t)CO * CO * 2));
  float* w3   = (float*)(W + alloc((size_t)NB * NS * 3 * 4));
  int*   idx3 = (int*)(W + alloc((size_t)NB * NS * 3 * 4));
  float* st1  = (float*)(W + alloc(512 * 4));
  float* st2  = (float*)(W + alloc(512 * 4));
  size_t y2_off = alloc((size_t)NB * NS * CO * 2);                     // 33.6MB bf16
  bool full = (ws_size >= off);
  ushort_t* y2b = full ? (ushort_t*)(W + y2_off) : (ushort_t*)d_out;
  // pbuf (16.8MB, transient, consumed before any y2 write) aliases y2 region
  float* pbuf = full ? (float*)(W + y2_off) : (float*)d_out;

  hipLaunchKernelGGL(topk_chunk_kernel, dim3(NS / 512, NCHUNK, NB), dim3(256), 0,
                     stream, xyz_prev, xyz_skip, pbuf);
  hipLaunchKernelGGL(topk_merge_kernel, dim3(NB * NS / 256), dim3(256), 0, stream,
                     pbuf, w3, idx3);
  hipLaunchKernelGGL(wcast_kernel, dim3((CO * CIN / 4 + CO * CO / 4 + 255) / 256),
                     dim3(256), 0, stream, W1, W2, W1b, W2b, st1, st2);
  hipLaunchKernelGGL(ppT_kernel, dim3(NP / 64, CP / 64, NB), dim3(256), 0, stream,
                     points_prev, pptT);
  hipLaunchKernelGGL(skipT_kernel, dim3(NS / 64, CS / 64, NB), dim3(256), 0, stream,
                     points_skip, xsk);
  hipLaunchKernelGGL((gemm_fused_kernel<0>), dim3(1024), dim3(256), 0, stream,
                     pptT, xsk, w3, idx3, W1b, y1b, st1,
                     (const float*)nullptr, (const float*)nullptr,
                     (const float*)nullptr);
  hipLaunchKernelGGL((gemm_fused_kernel<1>), dim3(1024), dim3(256), 0, stream,
                     y1b, (const ushort_t*)nullptr, (const float*)nullptr,
                     (const int*)nullptr, W2b, y2b, st2, st1, g1, b1);
  if (full) {
    hipLaunchKernelGGL(bnrelu_tr_kernel, dim3(NS / 64, CO / 64, NB), dim3(256), 0,
                       stream, y2b, st2, g2, b2, out);
  } else {
    float* stage = (float*)d_ws;
    hipLaunchKernelGGL(bnrelu_tr_kernel, dim3(NS / 64, CO / 64, NB), dim3(256), 0,
                       stream, y2b, st2, g2, b2, stage);
    hipMemcpyAsync(out, stage, (size_t)NB * NS * CO * 4, hipMemcpyDeviceToDevice,
                   stream);
  }
}